// Round 1
// baseline (3346.287 us; speedup 1.0000x reference)
//
#include <hip/hip_runtime.h>

#define NB 4
#define IH 512
#define IW 512
#define FH 256
#define FW 256
#define CF 96
#define C1 99
#define HWI (IH*IW)     /* 262144 */
#define HWF (FH*FW)     /* 65536  */

static __device__ __forceinline__ float sigmoidf_(float x) {
    return 1.0f / (1.0f + __expf(-x));
}

// ---------------------------------------------------------------------------
// Pass 1 of local_kernel_warp: horizontal 5-tap kernel warp of img -> img_row
// sample position: y = h + 0.5*fy (clamped), x = w + 0.5*fx + (k-2)*(1/a)*511/512
// ---------------------------------------------------------------------------
__global__ __launch_bounds__(256)
void lkw_row_kernel(const float* __restrict__ img,
                    const float* __restrict__ flow,
                    const float* __restrict__ kp,
                    float* __restrict__ img_row) {
    int idx = blockIdx.x * blockDim.x + threadIdx.x;
    if (idx >= NB * HWI) return;
    int w = idx & (IW - 1);
    int h = (idx >> 9) & (IH - 1);
    int b = idx >> 18;

    const float* kpb = kp + (size_t)b * 11 * HWI + h * IW + w;
    // softmax over channels 0..4
    float p[5];
    float m = -1e30f;
    #pragma unroll
    for (int k = 0; k < 5; k++) { p[k] = kpb[k * HWI]; m = fmaxf(m, p[k]); }
    float s = 0.f;
    #pragma unroll
    for (int k = 0; k < 5; k++) { p[k] = __expf(p[k] - m); s += p[k]; }
    float invs = 1.f / s;
    float a = sigmoidf_(kpb[10 * HWI]) + 0.5f;
    float inva = 1.f / a;

    float fx = flow[((size_t)b * 2 + 0) * HWI + h * IW + w];
    float fy = flow[((size_t)b * 2 + 1) * HWI + h * IW + w];

    float y = (float)h + 0.5f * fy;
    y = fminf(fmaxf(y, 0.f), (float)(IH - 1));
    float y0f = floorf(y);
    int y0 = (int)y0f;
    int y1 = min(y0 + 1, IH - 1);
    float wy = y - y0f;

    float xbase = (float)w + 0.5f * fx;
    const float sc = (float)(IW - 1) / (float)IW;  // 511/512

    const float* imb = img + (size_t)b * 3 * HWI;
    float acc0 = 0.f, acc1 = 0.f, acc2 = 0.f;
    #pragma unroll
    for (int k = 0; k < 5; k++) {
        float x = xbase + (float)(k - 2) * inva * sc;
        x = fminf(fmaxf(x, 0.f), (float)(IW - 1));
        float x0f = floorf(x);
        int x0 = (int)x0f;
        int x1 = min(x0 + 1, IW - 1);
        float wx = x - x0f;
        float wk = p[k] * invs;
        float w00 = (1.f - wx) * (1.f - wy) * wk;
        float w01 = wx * (1.f - wy) * wk;
        float w10 = (1.f - wx) * wy * wk;
        float w11 = wx * wy * wk;
        int i00 = y0 * IW + x0, i01 = y0 * IW + x1;
        int i10 = y1 * IW + x0, i11 = y1 * IW + x1;
        acc0 += w00 * imb[i00] + w01 * imb[i01] + w10 * imb[i10] + w11 * imb[i11];
        acc1 += w00 * imb[HWI + i00] + w01 * imb[HWI + i01] + w10 * imb[HWI + i10] + w11 * imb[HWI + i11];
        acc2 += w00 * imb[2 * HWI + i00] + w01 * imb[2 * HWI + i01] + w10 * imb[2 * HWI + i10] + w11 * imb[2 * HWI + i11];
    }
    img_row[(size_t)b * 3 * HWI + h * IW + w] = acc0;
    img_row[(size_t)b * 3 * HWI + HWI + h * IW + w] = acc1;
    img_row[(size_t)b * 3 * HWI + 2 * HWI + h * IW + w] = acc2;
}

// ---------------------------------------------------------------------------
// Pass 2: vertical 5-tap (x is exactly integer w) -> warped_img (output 1)
// sample position: y = h + (k-2)*a*511/512 (clamped), x = w
// ---------------------------------------------------------------------------
__global__ __launch_bounds__(256)
void lkw_col_kernel(const float* __restrict__ img_row,
                    const float* __restrict__ kp,
                    float* __restrict__ out1) {
    int idx = blockIdx.x * blockDim.x + threadIdx.x;
    if (idx >= NB * HWI) return;
    int w = idx & (IW - 1);
    int h = (idx >> 9) & (IH - 1);
    int b = idx >> 18;

    const float* kpb = kp + (size_t)b * 11 * HWI + h * IW + w;
    float p[5];
    float m = -1e30f;
    #pragma unroll
    for (int k = 0; k < 5; k++) { p[k] = kpb[(5 + k) * HWI]; m = fmaxf(m, p[k]); }
    float s = 0.f;
    #pragma unroll
    for (int k = 0; k < 5; k++) { p[k] = __expf(p[k] - m); s += p[k]; }
    float invs = 1.f / s;
    float a = sigmoidf_(kpb[10 * HWI]) + 0.5f;

    const float sc = (float)(IH - 1) / (float)IH;  // 511/512
    const float* irb = img_row + (size_t)b * 3 * HWI;
    float acc0 = 0.f, acc1 = 0.f, acc2 = 0.f;
    #pragma unroll
    for (int k = 0; k < 5; k++) {
        float y = (float)h + (float)(k - 2) * a * sc;
        y = fminf(fmaxf(y, 0.f), (float)(IH - 1));
        float y0f = floorf(y);
        int y0 = (int)y0f;
        int y1 = min(y0 + 1, IH - 1);
        float wy = y - y0f;
        float wk = p[k] * invs;
        float w0 = (1.f - wy) * wk, w1 = wy * wk;
        int i0 = y0 * IW + w, i1 = y1 * IW + w;
        acc0 += w0 * irb[i0] + w1 * irb[i1];
        acc1 += w0 * irb[HWI + i0] + w1 * irb[HWI + i1];
        acc2 += w0 * irb[2 * HWI + i0] + w1 * irb[2 * HWI + i1];
    }
    out1[(size_t)b * 3 * HWI + h * IW + w] = acc0;
    out1[(size_t)b * 3 * HWI + HWI + h * IW + w] = acc1;
    out1[(size_t)b * 3 * HWI + 2 * HWI + h * IW + w] = acc2;
}

// ---------------------------------------------------------------------------
// jax.image.resize('linear', antialias=True), exact 2x downsample:
// separable [1,3,3,1]/8 taps at {2i-1..2i+2}; borders renormalized:
// i==0 -> taps (0,1,2) = (3,3,1)/7 ; i==last -> (n-3,n-2,n-1) = (1,3,3)/7
// ---------------------------------------------------------------------------
static __device__ __forceinline__ void ds_taps(int i, int n_in, int t[4], float wt[4]) {
    int n_out = n_in >> 1;
    if (i == 0) {
        t[0] = 0; t[1] = 0; t[2] = 1; t[3] = 2;
        wt[0] = 0.f; wt[1] = 3.f / 7.f; wt[2] = 3.f / 7.f; wt[3] = 1.f / 7.f;
    } else if (i == n_out - 1) {
        t[0] = n_in - 3; t[1] = n_in - 2; t[2] = n_in - 1; t[3] = n_in - 1;
        wt[0] = 1.f / 7.f; wt[1] = 3.f / 7.f; wt[2] = 3.f / 7.f; wt[3] = 0.f;
    } else {
        t[0] = 2 * i - 1; t[1] = 2 * i; t[2] = 2 * i + 1; t[3] = 2 * i + 2;
        wt[0] = 0.125f; wt[1] = 0.375f; wt[2] = 0.375f; wt[3] = 0.125f;
    }
}

__global__ __launch_bounds__(256)
void downsample2x_kernel(const float* __restrict__ src, float* __restrict__ dst,
                         int BC, float mul) {
    int idx = blockIdx.x * blockDim.x + threadIdx.x;
    if (idx >= BC * HWF) return;
    int j = idx & (FW - 1);
    int i = (idx >> 8) & (FH - 1);
    int bc = idx >> 16;

    int tx[4], ty[4];
    float wx[4], wy[4];
    ds_taps(j, IW, tx, wx);
    ds_taps(i, IH, ty, wy);
    const float* s = src + (size_t)bc * HWI;
    float acc = 0.f;
    #pragma unroll
    for (int a = 0; a < 4; a++) {
        if (wy[a] == 0.f) continue;
        const float* rp = s + (size_t)ty[a] * IW;
        float row = wx[0] * rp[tx[0]] + wx[1] * rp[tx[1]] + wx[2] * rp[tx[2]] + wx[3] * rp[tx[3]];
        acc += wy[a] * row;
    }
    dst[idx] = acc * mul;
}

// ---------------------------------------------------------------------------
// backward_warp(features, flow_scaled) -> warped_feat (written to out0 region)
// ---------------------------------------------------------------------------
__global__ __launch_bounds__(256)
void warp_feat_kernel(const float* __restrict__ feat,
                      const float* __restrict__ flow_s,
                      float* __restrict__ wfeat) {
    int idx = blockIdx.x * blockDim.x + threadIdx.x;
    if (idx >= NB * HWF) return;
    int j = idx & (FW - 1);
    int i = (idx >> 8) & (FH - 1);
    int b = idx >> 16;

    float fx = flow_s[((size_t)b * 2 + 0) * HWF + i * FW + j];
    float fy = flow_s[((size_t)b * 2 + 1) * HWF + i * FW + j];
    float u = (float)j + 0.5f * fx;
    float v = (float)i + 0.5f * fy;
    bool valid = (u >= 0.f) && (u <= (float)(FW - 1)) && (v >= 0.f) && (v <= (float)(FH - 1));
    float x = fminf(fmaxf(u, 0.f), (float)(FW - 1));
    float y = fminf(fmaxf(v, 0.f), (float)(FH - 1));
    float x0f = floorf(x), y0f = floorf(y);
    int x0 = (int)x0f, y0 = (int)y0f;
    int x1 = min(x0 + 1, FW - 1), y1 = min(y0 + 1, FH - 1);
    float wx = x - x0f, wy = y - y0f;
    float w00 = (1.f - wx) * (1.f - wy), w01 = wx * (1.f - wy);
    float w10 = (1.f - wx) * wy, w11 = wx * wy;
    if (!valid) { w00 = w01 = w10 = w11 = 0.f; }

    const float* fb = feat + (size_t)b * CF * HWF;
    float* ob = wfeat + (size_t)b * CF * HWF;
    int i00 = y0 * FW + x0, i01 = y0 * FW + x1;
    int i10 = y1 * FW + x0, i11 = y1 * FW + x1;
    int o = i * FW + j;
    for (int c = 0; c < CF; c++) {
        const float* fc = fb + (size_t)c * HWF;
        ob[(size_t)c * HWF + o] = w00 * fc[i00] + w01 * fc[i01] + w10 * fc[i10] + w11 * fc[i11];
    }
}

// ---------------------------------------------------------------------------
// conv1: relu( conv3x3(concat(wfeat, img_down), w1) + b1 ) -> t1
// block = 16x16 spatial tile for 4 output channels; weights via uniform s_loads
// ---------------------------------------------------------------------------
__global__ __launch_bounds__(256)
void conv1_kernel(const float* __restrict__ wfeat,  // [B,96,256,256]
                  const float* __restrict__ imgd,   // [B,3,256,256]
                  const float* __restrict__ w1,     // [96,99,3,3]
                  const float* __restrict__ b1,
                  float* __restrict__ t1) {
    __shared__ float st[18 * 18];
    int tid = threadIdx.x;
    int tx = tid & 15, ty = tid >> 4;
    int j0 = blockIdx.x * 16, i0 = blockIdx.y * 16;
    int z = blockIdx.z;
    int b = z / (CF / 4);
    int cog = z % (CF / 4);
    int co0 = cog * 4;

    const float* xb = wfeat + (size_t)b * CF * HWF;
    const float* db = imgd + (size_t)b * 3 * HWF;
    float acc[4] = {0.f, 0.f, 0.f, 0.f};

    for (int ci = 0; ci < C1; ci++) {
        const float* src = (ci < CF) ? (xb + (size_t)ci * HWF) : (db + (size_t)(ci - CF) * HWF);
        __syncthreads();
        for (int p = tid; p < 18 * 18; p += 256) {
            int tiy = p / 18, tjx = p - tiy * 18;
            int gi = i0 - 1 + tiy, gj = j0 - 1 + tjx;
            float v = 0.f;
            if (gi >= 0 && gi < FH && gj >= 0 && gj < FW) v = src[gi * FW + gj];
            st[p] = v;
        }
        __syncthreads();
        const float* wrow = w1 + (size_t)co0 * C1 * 9 + ci * 9;
        #pragma unroll
        for (int dy = 0; dy < 3; dy++) {
            float x0v = st[(ty + dy) * 18 + tx];
            float x1v = st[(ty + dy) * 18 + tx + 1];
            float x2v = st[(ty + dy) * 18 + tx + 2];
            #pragma unroll
            for (int g = 0; g < 4; g++) {
                const float* wg = wrow + (size_t)g * C1 * 9 + dy * 3;
                acc[g] += wg[0] * x0v + wg[1] * x1v + wg[2] * x2v;
            }
        }
    }
    int oi = i0 + ty, oj = j0 + tx;
    #pragma unroll
    for (int g = 0; g < 4; g++) {
        float v = acc[g] + b1[co0 + g];
        t1[(size_t)(b * CF + co0 + g) * HWF + oi * FW + oj] = fmaxf(v, 0.f);
    }
}

// ---------------------------------------------------------------------------
// conv2: out0 = wfeat (already in out0, read in-place) + conv3x3(t1, w2) + b2
// ---------------------------------------------------------------------------
__global__ __launch_bounds__(256)
void conv2_kernel(const float* __restrict__ t1,
                  const float* __restrict__ w2,   // [96,96,3,3]
                  const float* __restrict__ b2,
                  float* __restrict__ io) {
    __shared__ float st[18 * 18];
    int tid = threadIdx.x;
    int tx = tid & 15, ty = tid >> 4;
    int j0 = blockIdx.x * 16, i0 = blockIdx.y * 16;
    int z = blockIdx.z;
    int b = z / (CF / 4);
    int cog = z % (CF / 4);
    int co0 = cog * 4;

    const float* xb = t1 + (size_t)b * CF * HWF;
    float acc[4] = {0.f, 0.f, 0.f, 0.f};

    for (int ci = 0; ci < CF; ci++) {
        const float* src = xb + (size_t)ci * HWF;
        __syncthreads();
        for (int p = tid; p < 18 * 18; p += 256) {
            int tiy = p / 18, tjx = p - tiy * 18;
            int gi = i0 - 1 + tiy, gj = j0 - 1 + tjx;
            float v = 0.f;
            if (gi >= 0 && gi < FH && gj >= 0 && gj < FW) v = src[gi * FW + gj];
            st[p] = v;
        }
        __syncthreads();
        const float* wrow = w2 + (size_t)co0 * CF * 9 + ci * 9;
        #pragma unroll
        for (int dy = 0; dy < 3; dy++) {
            float x0v = st[(ty + dy) * 18 + tx];
            float x1v = st[(ty + dy) * 18 + tx + 1];
            float x2v = st[(ty + dy) * 18 + tx + 2];
            #pragma unroll
            for (int g = 0; g < 4; g++) {
                const float* wg = wrow + (size_t)g * CF * 9 + dy * 3;
                acc[g] += wg[0] * x0v + wg[1] * x1v + wg[2] * x2v;
            }
        }
    }
    int oi = i0 + ty, oj = j0 + tx;
    #pragma unroll
    for (int g = 0; g < 4; g++) {
        size_t off = (size_t)(b * CF + co0 + g) * HWF + oi * FW + oj;
        io[off] = io[off] + acc[g] + b2[co0 + g];
    }
}

extern "C" void kernel_launch(void* const* d_in, const int* in_sizes, int n_in,
                              void* d_out, int out_size, void* d_ws, size_t ws_size,
                              hipStream_t stream) {
    const float* img  = (const float*)d_in[0];
    const float* feat = (const float*)d_in[1];
    const float* flow = (const float*)d_in[2];
    const float* kp   = (const float*)d_in[3];
    const float* w1   = (const float*)d_in[4];
    const float* b1   = (const float*)d_in[5];
    const float* w2   = (const float*)d_in[6];
    const float* b2   = (const float*)d_in[7];

    float* out0 = (float*)d_out;                       // [B,96,256,256] = wfeat + fused
    float* out1 = out0 + (size_t)NB * CF * HWF;        // [B,3,512,512]  = warped_img

    float* ws = (float*)d_ws;
    float* img_row = ws;                               // NB*3*HWI   = 3,145,728 floats
    float* flow_s  = img_row + (size_t)NB * 3 * HWI;   // NB*2*HWF   =   524,288
    float* img_d   = flow_s + (size_t)NB * 2 * HWF;    // NB*3*HWF   =   786,432
    float* t1      = img_d + (size_t)NB * 3 * HWF;     // NB*96*HWF  = 25,165,824
    // total ws use: 29,622,272 floats = ~118.5 MB

    int n_img = NB * HWI;
    hipLaunchKernelGGL(lkw_row_kernel, dim3((n_img + 255) / 256), dim3(256), 0, stream,
                       img, flow, kp, img_row);
    hipLaunchKernelGGL(lkw_col_kernel, dim3((n_img + 255) / 256), dim3(256), 0, stream,
                       img_row, kp, out1);
    hipLaunchKernelGGL(downsample2x_kernel, dim3((NB * 3 * HWF + 255) / 256), dim3(256), 0, stream,
                       out1, img_d, NB * 3, 1.0f);
    hipLaunchKernelGGL(downsample2x_kernel, dim3((NB * 2 * HWF + 255) / 256), dim3(256), 0, stream,
                       flow, flow_s, NB * 2, 0.5f);
    hipLaunchKernelGGL(warp_feat_kernel, dim3((NB * HWF + 255) / 256), dim3(256), 0, stream,
                       feat, flow_s, out0);
    hipLaunchKernelGGL(conv1_kernel, dim3(FW / 16, FH / 16, NB * (CF / 4)), dim3(256), 0, stream,
                       out0, img_d, w1, b1, t1);
    hipLaunchKernelGGL(conv2_kernel, dim3(FW / 16, FH / 16, NB * (CF / 4)), dim3(256), 0, stream,
                       t1, w2, b2, out0);
}

// Round 3
// 752.438 us; speedup vs baseline: 4.4473x; 4.4473x over previous
//
#include <hip/hip_runtime.h>

#define NB 4
#define IH 512
#define IW 512
#define FH 256
#define FW 256
#define CF 96
#define C1 99
#define HWI (IH*IW)     /* 262144 */
#define HWF (FH*FW)     /* 65536  */
#define LDK 40          /* padded K stride (shorts) in LDS: 80B */

typedef short s8v __attribute__((ext_vector_type(8)));
typedef short s4v __attribute__((ext_vector_type(4)));
typedef float f4v __attribute__((ext_vector_type(4)));

static __device__ __forceinline__ float sigmoidf_(float x) {
    return 1.0f / (1.0f + __expf(-x));
}
static __device__ __forceinline__ unsigned short f2bf(float f) {
    unsigned int u = __float_as_uint(f);
    unsigned int r = (u + 0x7fffu + ((u >> 16) & 1u)) >> 16;
    return (unsigned short)r;
}

// ---------------------------------------------------------------------------
// Pass 1 of local_kernel_warp (validated R1)
// ---------------------------------------------------------------------------
__global__ __launch_bounds__(256)
void lkw_row_kernel(const float* __restrict__ img,
                    const float* __restrict__ flow,
                    const float* __restrict__ kp,
                    float* __restrict__ img_row) {
    int idx = blockIdx.x * blockDim.x + threadIdx.x;
    if (idx >= NB * HWI) return;
    int w = idx & (IW - 1);
    int h = (idx >> 9) & (IH - 1);
    int b = idx >> 18;

    const float* kpb = kp + (size_t)b * 11 * HWI + h * IW + w;
    float p[5];
    float m = -1e30f;
    #pragma unroll
    for (int k = 0; k < 5; k++) { p[k] = kpb[k * HWI]; m = fmaxf(m, p[k]); }
    float s = 0.f;
    #pragma unroll
    for (int k = 0; k < 5; k++) { p[k] = __expf(p[k] - m); s += p[k]; }
    float invs = 1.f / s;
    float a = sigmoidf_(kpb[10 * HWI]) + 0.5f;
    float inva = 1.f / a;

    float fx = flow[((size_t)b * 2 + 0) * HWI + h * IW + w];
    float fy = flow[((size_t)b * 2 + 1) * HWI + h * IW + w];

    float y = (float)h + 0.5f * fy;
    y = fminf(fmaxf(y, 0.f), (float)(IH - 1));
    float y0f = floorf(y);
    int y0 = (int)y0f;
    int y1 = min(y0 + 1, IH - 1);
    float wy = y - y0f;

    float xbase = (float)w + 0.5f * fx;
    const float sc = (float)(IW - 1) / (float)IW;

    const float* imb = img + (size_t)b * 3 * HWI;
    float acc0 = 0.f, acc1 = 0.f, acc2 = 0.f;
    #pragma unroll
    for (int k = 0; k < 5; k++) {
        float x = xbase + (float)(k - 2) * inva * sc;
        x = fminf(fmaxf(x, 0.f), (float)(IW - 1));
        float x0f = floorf(x);
        int x0 = (int)x0f;
        int x1 = min(x0 + 1, IW - 1);
        float wx = x - x0f;
        float wk = p[k] * invs;
        float w00 = (1.f - wx) * (1.f - wy) * wk;
        float w01 = wx * (1.f - wy) * wk;
        float w10 = (1.f - wx) * wy * wk;
        float w11 = wx * wy * wk;
        int i00 = y0 * IW + x0, i01 = y0 * IW + x1;
        int i10 = y1 * IW + x0, i11 = y1 * IW + x1;
        acc0 += w00 * imb[i00] + w01 * imb[i01] + w10 * imb[i10] + w11 * imb[i11];
        acc1 += w00 * imb[HWI + i00] + w01 * imb[HWI + i01] + w10 * imb[HWI + i10] + w11 * imb[HWI + i11];
        acc2 += w00 * imb[2 * HWI + i00] + w01 * imb[2 * HWI + i01] + w10 * imb[2 * HWI + i10] + w11 * imb[2 * HWI + i11];
    }
    img_row[(size_t)b * 3 * HWI + h * IW + w] = acc0;
    img_row[(size_t)b * 3 * HWI + HWI + h * IW + w] = acc1;
    img_row[(size_t)b * 3 * HWI + 2 * HWI + h * IW + w] = acc2;
}

// ---------------------------------------------------------------------------
// Pass 2 (validated R1)
// ---------------------------------------------------------------------------
__global__ __launch_bounds__(256)
void lkw_col_kernel(const float* __restrict__ img_row,
                    const float* __restrict__ kp,
                    float* __restrict__ out1) {
    int idx = blockIdx.x * blockDim.x + threadIdx.x;
    if (idx >= NB * HWI) return;
    int w = idx & (IW - 1);
    int h = (idx >> 9) & (IH - 1);
    int b = idx >> 18;

    const float* kpb = kp + (size_t)b * 11 * HWI + h * IW + w;
    float p[5];
    float m = -1e30f;
    #pragma unroll
    for (int k = 0; k < 5; k++) { p[k] = kpb[(5 + k) * HWI]; m = fmaxf(m, p[k]); }
    float s = 0.f;
    #pragma unroll
    for (int k = 0; k < 5; k++) { p[k] = __expf(p[k] - m); s += p[k]; }
    float invs = 1.f / s;
    float a = sigmoidf_(kpb[10 * HWI]) + 0.5f;

    const float sc = (float)(IH - 1) / (float)IH;
    const float* irb = img_row + (size_t)b * 3 * HWI;
    float acc0 = 0.f, acc1 = 0.f, acc2 = 0.f;
    #pragma unroll
    for (int k = 0; k < 5; k++) {
        float y = (float)h + (float)(k - 2) * a * sc;
        y = fminf(fmaxf(y, 0.f), (float)(IH - 1));
        float y0f = floorf(y);
        int y0 = (int)y0f;
        int y1 = min(y0 + 1, IH - 1);
        float wy = y - y0f;
        float wk = p[k] * invs;
        float w0 = (1.f - wy) * wk, w1 = wy * wk;
        int i0 = y0 * IW + w, i1 = y1 * IW + w;
        acc0 += w0 * irb[i0] + w1 * irb[i1];
        acc1 += w0 * irb[HWI + i0] + w1 * irb[HWI + i1];
        acc2 += w0 * irb[2 * HWI + i0] + w1 * irb[2 * HWI + i1];
    }
    out1[(size_t)b * 3 * HWI + h * IW + w] = acc0;
    out1[(size_t)b * 3 * HWI + HWI + h * IW + w] = acc1;
    out1[(size_t)b * 3 * HWI + 2 * HWI + h * IW + w] = acc2;
}

// ---------------------------------------------------------------------------
// antialiased 2x downsample taps (validated R1)
// ---------------------------------------------------------------------------
static __device__ __forceinline__ void ds_taps(int i, int n_in, int t[4], float wt[4]) {
    int n_out = n_in >> 1;
    if (i == 0) {
        t[0] = 0; t[1] = 0; t[2] = 1; t[3] = 2;
        wt[0] = 0.f; wt[1] = 3.f / 7.f; wt[2] = 3.f / 7.f; wt[3] = 1.f / 7.f;
    } else if (i == n_out - 1) {
        t[0] = n_in - 3; t[1] = n_in - 2; t[2] = n_in - 1; t[3] = n_in - 1;
        wt[0] = 1.f / 7.f; wt[1] = 3.f / 7.f; wt[2] = 3.f / 7.f; wt[3] = 0.f;
    } else {
        t[0] = 2 * i - 1; t[1] = 2 * i; t[2] = 2 * i + 1; t[3] = 2 * i + 2;
        wt[0] = 0.125f; wt[1] = 0.375f; wt[2] = 0.375f; wt[3] = 0.125f;
    }
}

__global__ __launch_bounds__(256)
void downsample2x_kernel(const float* __restrict__ src, float* __restrict__ dst,
                         int BC, float mul) {
    int idx = blockIdx.x * blockDim.x + threadIdx.x;
    if (idx >= BC * HWF) return;
    int j = idx & (FW - 1);
    int i = (idx >> 8) & (FH - 1);
    int bc = idx >> 16;

    int tx[4], ty[4];
    float wx[4], wy[4];
    ds_taps(j, IW, tx, wx);
    ds_taps(i, IH, ty, wy);
    const float* s = src + (size_t)bc * HWI;
    float acc = 0.f;
    #pragma unroll
    for (int a = 0; a < 4; a++) {
        if (wy[a] == 0.f) continue;
        const float* rp = s + (size_t)ty[a] * IW;
        float row = wx[0] * rp[tx[0]] + wx[1] * rp[tx[1]] + wx[2] * rp[tx[2]] + wx[3] * rp[tx[3]];
        acc += wy[a] * row;
    }
    dst[idx] = acc * mul;
}

// ---------------------------------------------------------------------------
// img downsample -> channels-last bf16 xin slots [96..128)
// ---------------------------------------------------------------------------
__global__ __launch_bounds__(256)
void imgdown_cl_kernel(const float* __restrict__ out1, short* __restrict__ xin) {
    int idx = blockIdx.x * blockDim.x + threadIdx.x;
    if (idx >= NB * HWF) return;
    int j = idx & (FW - 1);
    int i = (idx >> 8) & (FH - 1);
    int b = idx >> 16;

    int tx[4], ty[4];
    float wx[4], wy[4];
    ds_taps(j, IW, tx, wx);
    ds_taps(i, IH, ty, wy);
    const float* s = out1 + (size_t)b * 3 * HWI;
    float acc[3] = {0.f, 0.f, 0.f};
    #pragma unroll
    for (int a = 0; a < 4; a++) {
        if (wy[a] == 0.f) continue;
        #pragma unroll
        for (int c = 0; c < 3; c++) {
            const float* rp = s + (size_t)c * HWI + (size_t)ty[a] * IW;
            float row = wx[0] * rp[tx[0]] + wx[1] * rp[tx[1]] + wx[2] * rp[tx[2]] + wx[3] * rp[tx[3]];
            acc[c] += wy[a] * row;
        }
    }
    short* dst = xin + ((size_t)(b * FH + i) * FW + j) * 128 + 96;
    s8v g0 = { (short)f2bf(acc[0]), (short)f2bf(acc[1]), (short)f2bf(acc[2]), 0, 0, 0, 0, 0 };
    s8v z  = { 0, 0, 0, 0, 0, 0, 0, 0 };
    *(s8v*)(dst)      = g0;
    *(s8v*)(dst + 8)  = z;
    *(s8v*)(dst + 16) = z;
    *(s8v*)(dst + 24) = z;
}

// ---------------------------------------------------------------------------
// backward_warp(features) -> out0 (fp32 planar) + xin slots [0..96) (bf16 cl)
// ---------------------------------------------------------------------------
__global__ __launch_bounds__(256)
void warp_feat_cl_kernel(const float* __restrict__ feat,
                         const float* __restrict__ flow_s,
                         float* __restrict__ wfeat,
                         short* __restrict__ xin) {
    int idx = blockIdx.x * blockDim.x + threadIdx.x;
    if (idx >= NB * HWF) return;
    int j = idx & (FW - 1);
    int i = (idx >> 8) & (FH - 1);
    int b = idx >> 16;

    float fx = flow_s[((size_t)b * 2 + 0) * HWF + i * FW + j];
    float fy = flow_s[((size_t)b * 2 + 1) * HWF + i * FW + j];
    float u = (float)j + 0.5f * fx;
    float v = (float)i + 0.5f * fy;
    bool valid = (u >= 0.f) && (u <= (float)(FW - 1)) && (v >= 0.f) && (v <= (float)(FH - 1));
    float x = fminf(fmaxf(u, 0.f), (float)(FW - 1));
    float y = fminf(fmaxf(v, 0.f), (float)(FH - 1));
    float x0f = floorf(x), y0f = floorf(y);
    int x0 = (int)x0f, y0 = (int)y0f;
    int x1 = min(x0 + 1, FW - 1), y1 = min(y0 + 1, FH - 1);
    float wxf = x - x0f, wyf = y - y0f;
    float w00 = (1.f - wxf) * (1.f - wyf), w01 = wxf * (1.f - wyf);
    float w10 = (1.f - wxf) * wyf, w11 = wxf * wyf;
    if (!valid) { w00 = w01 = w10 = w11 = 0.f; }

    const float* fb = feat + (size_t)b * CF * HWF;
    float* ob = wfeat + (size_t)b * CF * HWF;
    short* xrow = xin + ((size_t)(b * FH + i) * FW + j) * 128;
    int i00 = y0 * FW + x0, i01 = y0 * FW + x1;
    int i10 = y1 * FW + x0, i11 = y1 * FW + x1;
    int o = i * FW + j;
    for (int c = 0; c < CF; c += 2) {
        const float* fc0 = fb + (size_t)c * HWF;
        const float* fc1 = fb + (size_t)(c + 1) * HWF;
        float v0 = w00 * fc0[i00] + w01 * fc0[i01] + w10 * fc0[i10] + w11 * fc0[i11];
        float v1 = w00 * fc1[i00] + w01 * fc1[i01] + w10 * fc1[i10] + w11 * fc1[i11];
        ob[(size_t)c * HWF + o] = v0;
        ob[(size_t)(c + 1) * HWF + o] = v1;
        unsigned pk = (unsigned)f2bf(v0) | ((unsigned)f2bf(v1) << 16);
        *(unsigned*)(xrow + c) = pk;
    }
}

// ---------------------------------------------------------------------------
// Weight repack: w[co][ci][3][3] fp32 -> wA[off][co][KSTR] bf16
// ---------------------------------------------------------------------------
__global__ __launch_bounds__(256)
void cvt_w1_kernel(const float* __restrict__ w1, short* __restrict__ wA1) {
    int i = blockIdx.x * 256 + threadIdx.x;
    if (i >= 9 * 96 * 128) return;
    int ci = i & 127;
    int co = (i >> 7) % 96;
    int off = i / (96 * 128);
    float v = (ci < C1) ? w1[((size_t)co * C1 + ci) * 9 + off] : 0.f;
    wA1[i] = (short)f2bf(v);
}
__global__ __launch_bounds__(256)
void cvt_w2_kernel(const float* __restrict__ w2, short* __restrict__ wA2) {
    int i = blockIdx.x * 256 + threadIdx.x;
    if (i >= 9 * 96 * 96) return;
    int ci = i % 96;
    int co = (i / 96) % 96;
    int off = i / (96 * 96);
    wA2[i] = (short)f2bf(w2[((size_t)co * CF + ci) * 9 + off]);
}

// ---------------------------------------------------------------------------
// MFMA implicit-GEMM 3x3 conv. Staging FIX vs R2: each LDS row needs 64 B per
// 32-ci chunk; 2 threads/row x 32 B each (two float4), not 16 B (half rows
// of A/B LDS were uninitialized -> NaN).
// ---------------------------------------------------------------------------
template <int PASS>
__global__ __launch_bounds__(256)
void conv_mfma_kernel(const short* __restrict__ X,    // [b][h][w][KSTR] bf16
                      const short* __restrict__ W,    // [9][96][KSTR] bf16
                      const float* __restrict__ bias,
                      short* __restrict__ t1out,
                      float* __restrict__ out0) {
    constexpr int KSTR = (PASS == 1) ? 128 : 96;
    constexpr int KC = KSTR / 32;
    __shared__ short Als[96 * LDK];
    __shared__ short Bls[128 * LDK];

    const int bx = blockIdx.x;
    const int w0 = (bx & 1) * 128;
    const int h  = (bx >> 1) & (FH - 1);
    const int b  = bx >> 9;

    const int tid = threadIdx.x;
    const int lane = tid & 63;
    const int wv = tid >> 6;     // wave 0..3 -> n block [wv*32, wv*32+32)
    const int ln = lane & 15;
    const int q  = lane >> 4;

    f4v acc[6][2];
    #pragma unroll
    for (int mt = 0; mt < 6; mt++)
        #pragma unroll
        for (int nt = 0; nt < 2; nt++)
            acc[mt][nt] = (f4v){0.f, 0.f, 0.f, 0.f};

    const short* Xb = X + (size_t)(b * FH) * FW * KSTR;

    const int an = tid >> 1, ah = tid & 1;   // row = an, half = ah (32B each)

    for (int off = 0; off < 9; ++off) {
        const int dy = off / 3 - 1, dx = off % 3 - 1;
        const int hy = h + dy;
        const bool hok = (hy >= 0) && (hy < FH);
        const short* Xrow = Xb + (size_t)hy * FW * KSTR;
        const short* Woff = W + (size_t)off * 96 * KSTR;
        const int wc = w0 + an + dx;
        const bool cok = hok && (wc >= 0) && (wc < FW);

        for (int kc = 0; kc < KC; ++kc) {
            const int ci0 = kc * 32;
            __syncthreads();
            if (tid < 192) {
                const short* srcA = Woff + (size_t)an * KSTR + ci0 + ah * 16;
                short* dstA = Als + an * LDK + ah * 16;
                *(float4*)dstA = *(const float4*)srcA;
                *(float4*)(dstA + 8) = *(const float4*)(srcA + 8);
            }
            {
                float4 vb0 = {0.f, 0.f, 0.f, 0.f};
                float4 vb1 = {0.f, 0.f, 0.f, 0.f};
                if (cok) {
                    const short* srcB = Xrow + (size_t)wc * KSTR + ci0 + ah * 16;
                    vb0 = *(const float4*)srcB;
                    vb1 = *(const float4*)(srcB + 8);
                }
                short* dstB = Bls + an * LDK + ah * 16;
                *(float4*)dstB = vb0;
                *(float4*)(dstB + 8) = vb1;
            }
            __syncthreads();
            s8v bfr0 = *(const s8v*)(Bls + (wv * 32 + ln) * LDK + q * 8);
            s8v bfr1 = *(const s8v*)(Bls + (wv * 32 + 16 + ln) * LDK + q * 8);
            #pragma unroll
            for (int mt = 0; mt < 6; ++mt) {
                s8v afr = *(const s8v*)(Als + (mt * 16 + ln) * LDK + q * 8);
                acc[mt][0] = __builtin_amdgcn_mfma_f32_16x16x32_bf16(afr, bfr0, acc[mt][0], 0, 0, 0);
                acc[mt][1] = __builtin_amdgcn_mfma_f32_16x16x32_bf16(afr, bfr1, acc[mt][1], 0, 0, 0);
            }
        }
    }

    // epilogue: lane holds D[m = mt*16 + q*4 + r][n = w0 + wv*32 + nt*16 + ln]
    if (PASS == 1) {
        const size_t rowbase = (size_t)(b * FH + h) * FW;
        #pragma unroll
        for (int nt = 0; nt < 2; ++nt) {
            int pos = w0 + wv * 32 + nt * 16 + ln;
            short* dst = t1out + (rowbase + pos) * CF;
            #pragma unroll
            for (int mt = 0; mt < 6; ++mt) {
                int co0 = mt * 16 + q * 4;
                s4v pk;
                #pragma unroll
                for (int r = 0; r < 4; ++r) {
                    float v = acc[mt][nt][r] + bias[co0 + r];
                    pk[r] = (short)f2bf(fmaxf(v, 0.f));
                }
                *(s4v*)(dst + co0) = pk;
            }
        }
    } else {
        #pragma unroll
        for (int nt = 0; nt < 2; ++nt) {
            int pos = w0 + wv * 32 + nt * 16 + ln;
            #pragma unroll
            for (int mt = 0; mt < 6; ++mt) {
                int co0 = mt * 16 + q * 4;
                #pragma unroll
                for (int r = 0; r < 4; ++r) {
                    size_t o = (size_t)(b * CF + co0 + r) * HWF + (size_t)h * FW + pos;
                    out0[o] += acc[mt][nt][r] + bias[co0 + r];
                }
            }
        }
    }
}

extern "C" void kernel_launch(void* const* d_in, const int* in_sizes, int n_in,
                              void* d_out, int out_size, void* d_ws, size_t ws_size,
                              hipStream_t stream) {
    const float* img  = (const float*)d_in[0];
    const float* feat = (const float*)d_in[1];
    const float* flow = (const float*)d_in[2];
    const float* kp   = (const float*)d_in[3];
    const float* w1   = (const float*)d_in[4];
    const float* b1   = (const float*)d_in[5];
    const float* w2   = (const float*)d_in[6];
    const float* b2   = (const float*)d_in[7];

    float* out0 = (float*)d_out;                       // [B,96,256,256] fp32
    float* out1 = out0 + (size_t)NB * CF * HWF;        // [B,3,512,512]  fp32

    char* wsb = (char*)d_ws;
    short* wA1 = (short*)wsb;                                   //   221,184 B
    short* wA2 = (short*)(wsb + 221184);                        //   165,888 B
    short* xin = (short*)(wsb + 221184 + 165888);               // 67,108,864 B [b][h][w][128]
    char* region = wsb + 221184 + 165888 + 67108864;            // 50,331,648 B shared:
    short* t1cl    = (short*)region;                            //   t1 cl bf16 (convs)
    float* img_row = (float*)region;                            //   12.58 MB (dead before conv1)
    float* flow_s  = (float*)(region + 16777216);               //   2.1 MB (dead before conv1)

    int n_img = NB * HWI;
    hipLaunchKernelGGL(cvt_w1_kernel, dim3((9 * 96 * 128 + 255) / 256), dim3(256), 0, stream, w1, wA1);
    hipLaunchKernelGGL(cvt_w2_kernel, dim3((9 * 96 * 96 + 255) / 256), dim3(256), 0, stream, w2, wA2);
    hipLaunchKernelGGL(lkw_row_kernel, dim3((n_img + 255) / 256), dim3(256), 0, stream,
                       img, flow, kp, img_row);
    hipLaunchKernelGGL(lkw_col_kernel, dim3((n_img + 255) / 256), dim3(256), 0, stream,
                       img_row, kp, out1);
    hipLaunchKernelGGL(downsample2x_kernel, dim3((NB * 2 * HWF + 255) / 256), dim3(256), 0, stream,
                       flow, flow_s, NB * 2, 0.5f);
    hipLaunchKernelGGL(imgdown_cl_kernel, dim3((NB * HWF + 255) / 256), dim3(256), 0, stream,
                       out1, xin);
    hipLaunchKernelGGL(warp_feat_cl_kernel, dim3((NB * HWF + 255) / 256), dim3(256), 0, stream,
                       feat, flow_s, out0, xin);
    hipLaunchKernelGGL((conv_mfma_kernel<1>), dim3(NB * FH * 2), dim3(256), 0, stream,
                       xin, wA1, b1, t1cl, (float*)nullptr);
    hipLaunchKernelGGL((conv_mfma_kernel<2>), dim3(NB * FH * 2), dim3(256), 0, stream,
                       t1cl, wA2, b2, (short*)nullptr, out0);
}

// Round 4
// 687.785 us; speedup vs baseline: 4.8653x; 1.0940x over previous
//
#include <hip/hip_runtime.h>

#define NB 4
#define IH 512
#define IW 512
#define FH 256
#define FW 256
#define CF 96
#define C1 99
#define HWI (IH*IW)     /* 262144 */
#define HWF (FH*FW)     /* 65536  */
#define LDK 40          /* padded K stride (shorts) in LDS: 80B */

typedef short s8v __attribute__((ext_vector_type(8)));
typedef short s4v __attribute__((ext_vector_type(4)));
typedef float f4v __attribute__((ext_vector_type(4)));
typedef float f2v __attribute__((ext_vector_type(2), aligned(4)));  /* 4B-aligned pair load */

static __device__ __forceinline__ float sigmoidf_(float x) {
    return 1.0f / (1.0f + __expf(-x));
}
static __device__ __forceinline__ unsigned short f2bf(float f) {
    unsigned int u = __float_as_uint(f);
    unsigned int r = (u + 0x7fffu + ((u >> 16) & 1u)) >> 16;
    return (unsigned short)r;
}

// ---------------------------------------------------------------------------
// Pass 1 of local_kernel_warp (validated R1)
// ---------------------------------------------------------------------------
__global__ __launch_bounds__(256)
void lkw_row_kernel(const float* __restrict__ img,
                    const float* __restrict__ flow,
                    const float* __restrict__ kp,
                    float* __restrict__ img_row) {
    int idx = blockIdx.x * blockDim.x + threadIdx.x;
    if (idx >= NB * HWI) return;
    int w = idx & (IW - 1);
    int h = (idx >> 9) & (IH - 1);
    int b = idx >> 18;

    const float* kpb = kp + (size_t)b * 11 * HWI + h * IW + w;
    float p[5];
    float m = -1e30f;
    #pragma unroll
    for (int k = 0; k < 5; k++) { p[k] = kpb[k * HWI]; m = fmaxf(m, p[k]); }
    float s = 0.f;
    #pragma unroll
    for (int k = 0; k < 5; k++) { p[k] = __expf(p[k] - m); s += p[k]; }
    float invs = 1.f / s;
    float a = sigmoidf_(kpb[10 * HWI]) + 0.5f;
    float inva = 1.f / a;

    float fx = flow[((size_t)b * 2 + 0) * HWI + h * IW + w];
    float fy = flow[((size_t)b * 2 + 1) * HWI + h * IW + w];

    float y = (float)h + 0.5f * fy;
    y = fminf(fmaxf(y, 0.f), (float)(IH - 1));
    float y0f = floorf(y);
    int y0 = (int)y0f;
    int y1 = min(y0 + 1, IH - 1);
    float wy = y - y0f;

    float xbase = (float)w + 0.5f * fx;
    const float sc = (float)(IW - 1) / (float)IW;

    const float* imb = img + (size_t)b * 3 * HWI;
    float acc0 = 0.f, acc1 = 0.f, acc2 = 0.f;
    #pragma unroll
    for (int k = 0; k < 5; k++) {
        float x = xbase + (float)(k - 2) * inva * sc;
        x = fminf(fmaxf(x, 0.f), (float)(IW - 1));
        float x0f = floorf(x);
        int x0 = (int)x0f;
        int x1 = min(x0 + 1, IW - 1);
        float wx = x - x0f;
        float wk = p[k] * invs;
        float w00 = (1.f - wx) * (1.f - wy) * wk;
        float w01 = wx * (1.f - wy) * wk;
        float w10 = (1.f - wx) * wy * wk;
        float w11 = wx * wy * wk;
        int i00 = y0 * IW + x0, i01 = y0 * IW + x1;
        int i10 = y1 * IW + x0, i11 = y1 * IW + x1;
        acc0 += w00 * imb[i00] + w01 * imb[i01] + w10 * imb[i10] + w11 * imb[i11];
        acc1 += w00 * imb[HWI + i00] + w01 * imb[HWI + i01] + w10 * imb[HWI + i10] + w11 * imb[HWI + i11];
        acc2 += w00 * imb[2 * HWI + i00] + w01 * imb[2 * HWI + i01] + w10 * imb[2 * HWI + i10] + w11 * imb[2 * HWI + i11];
    }
    img_row[(size_t)b * 3 * HWI + h * IW + w] = acc0;
    img_row[(size_t)b * 3 * HWI + HWI + h * IW + w] = acc1;
    img_row[(size_t)b * 3 * HWI + 2 * HWI + h * IW + w] = acc2;
}

// ---------------------------------------------------------------------------
// Pass 2 (validated R1)
// ---------------------------------------------------------------------------
__global__ __launch_bounds__(256)
void lkw_col_kernel(const float* __restrict__ img_row,
                    const float* __restrict__ kp,
                    float* __restrict__ out1) {
    int idx = blockIdx.x * blockDim.x + threadIdx.x;
    if (idx >= NB * HWI) return;
    int w = idx & (IW - 1);
    int h = (idx >> 9) & (IH - 1);
    int b = idx >> 18;

    const float* kpb = kp + (size_t)b * 11 * HWI + h * IW + w;
    float p[5];
    float m = -1e30f;
    #pragma unroll
    for (int k = 0; k < 5; k++) { p[k] = kpb[(5 + k) * HWI]; m = fmaxf(m, p[k]); }
    float s = 0.f;
    #pragma unroll
    for (int k = 0; k < 5; k++) { p[k] = __expf(p[k] - m); s += p[k]; }
    float invs = 1.f / s;
    float a = sigmoidf_(kpb[10 * HWI]) + 0.5f;

    const float sc = (float)(IH - 1) / (float)IH;
    const float* irb = img_row + (size_t)b * 3 * HWI;
    float acc0 = 0.f, acc1 = 0.f, acc2 = 0.f;
    #pragma unroll
    for (int k = 0; k < 5; k++) {
        float y = (float)h + (float)(k - 2) * a * sc;
        y = fminf(fmaxf(y, 0.f), (float)(IH - 1));
        float y0f = floorf(y);
        int y0 = (int)y0f;
        int y1 = min(y0 + 1, IH - 1);
        float wy = y - y0f;
        float wk = p[k] * invs;
        float w0 = (1.f - wy) * wk, w1 = wy * wk;
        int i0 = y0 * IW + w, i1 = y1 * IW + w;
        acc0 += w0 * irb[i0] + w1 * irb[i1];
        acc1 += w0 * irb[HWI + i0] + w1 * irb[HWI + i1];
        acc2 += w0 * irb[2 * HWI + i0] + w1 * irb[2 * HWI + i1];
    }
    out1[(size_t)b * 3 * HWI + h * IW + w] = acc0;
    out1[(size_t)b * 3 * HWI + HWI + h * IW + w] = acc1;
    out1[(size_t)b * 3 * HWI + 2 * HWI + h * IW + w] = acc2;
}

// ---------------------------------------------------------------------------
// antialiased 2x downsample taps (validated R1)
// ---------------------------------------------------------------------------
static __device__ __forceinline__ void ds_taps(int i, int n_in, int t[4], float wt[4]) {
    int n_out = n_in >> 1;
    if (i == 0) {
        t[0] = 0; t[1] = 0; t[2] = 1; t[3] = 2;
        wt[0] = 0.f; wt[1] = 3.f / 7.f; wt[2] = 3.f / 7.f; wt[3] = 1.f / 7.f;
    } else if (i == n_out - 1) {
        t[0] = n_in - 3; t[1] = n_in - 2; t[2] = n_in - 1; t[3] = n_in - 1;
        wt[0] = 1.f / 7.f; wt[1] = 3.f / 7.f; wt[2] = 3.f / 7.f; wt[3] = 0.f;
    } else {
        t[0] = 2 * i - 1; t[1] = 2 * i; t[2] = 2 * i + 1; t[3] = 2 * i + 2;
        wt[0] = 0.125f; wt[1] = 0.375f; wt[2] = 0.375f; wt[3] = 0.125f;
    }
}

__global__ __launch_bounds__(256)
void downsample2x_kernel(const float* __restrict__ src, float* __restrict__ dst,
                         int BC, float mul) {
    int idx = blockIdx.x * blockDim.x + threadIdx.x;
    if (idx >= BC * HWF) return;
    int j = idx & (FW - 1);
    int i = (idx >> 8) & (FH - 1);
    int bc = idx >> 16;

    int tx[4], ty[4];
    float wx[4], wy[4];
    ds_taps(j, IW, tx, wx);
    ds_taps(i, IH, ty, wy);
    const float* s = src + (size_t)bc * HWI;
    float acc = 0.f;
    #pragma unroll
    for (int a = 0; a < 4; a++) {
        if (wy[a] == 0.f) continue;
        const float* rp = s + (size_t)ty[a] * IW;
        float row = wx[0] * rp[tx[0]] + wx[1] * rp[tx[1]] + wx[2] * rp[tx[2]] + wx[3] * rp[tx[3]];
        acc += wy[a] * row;
    }
    dst[idx] = acc * mul;
}

// ---------------------------------------------------------------------------
// img downsample -> channels-last bf16 xin slots [96..128)
// ---------------------------------------------------------------------------
__global__ __launch_bounds__(256)
void imgdown_cl_kernel(const float* __restrict__ out1, short* __restrict__ xin) {
    int idx = blockIdx.x * blockDim.x + threadIdx.x;
    if (idx >= NB * HWF) return;
    int j = idx & (FW - 1);
    int i = (idx >> 8) & (FH - 1);
    int b = idx >> 16;

    int tx[4], ty[4];
    float wx[4], wy[4];
    ds_taps(j, IW, tx, wx);
    ds_taps(i, IH, ty, wy);
    const float* s = out1 + (size_t)b * 3 * HWI;
    float acc[3] = {0.f, 0.f, 0.f};
    #pragma unroll
    for (int a = 0; a < 4; a++) {
        if (wy[a] == 0.f) continue;
        #pragma unroll
        for (int c = 0; c < 3; c++) {
            const float* rp = s + (size_t)c * HWI + (size_t)ty[a] * IW;
            float row = wx[0] * rp[tx[0]] + wx[1] * rp[tx[1]] + wx[2] * rp[tx[2]] + wx[3] * rp[tx[3]];
            acc[c] += wy[a] * row;
        }
    }
    short* dst = xin + ((size_t)(b * FH + i) * FW + j) * 128 + 96;
    s8v g0 = { (short)f2bf(acc[0]), (short)f2bf(acc[1]), (short)f2bf(acc[2]), 0, 0, 0, 0, 0 };
    s8v z  = { 0, 0, 0, 0, 0, 0, 0, 0 };
    *(s8v*)(dst)      = g0;
    *(s8v*)(dst + 8)  = z;
    *(s8v*)(dst + 16) = z;
    *(s8v*)(dst + 24) = z;
}

// ---------------------------------------------------------------------------
// backward_warp(features) v2: thread = (pixel, group of 12 channels).
// 8x grid of R3 -> hides gather latency. Border clamp reformulated:
// x0 = min(floor(x), W-2), wx = x-x0  (identical result; x1=x0+1 always valid)
// ---------------------------------------------------------------------------
__global__ __launch_bounds__(256)
void warp_feat_cl_kernel(const float* __restrict__ feat,
                         const float* __restrict__ flow_s,
                         float* __restrict__ wfeat,
                         short* __restrict__ xin) {
    int t = blockIdx.x * 256 + threadIdx.x;   // [0, NB*HWF*8)
    int g = t & 7;                            // channel group: 12 channels
    int pix = t >> 3;                         // [0, NB*HWF)
    int j = pix & (FW - 1);
    int i = (pix >> 8) & (FH - 1);
    int b = pix >> 16;

    float fx = flow_s[((size_t)b * 2 + 0) * HWF + i * FW + j];
    float fy = flow_s[((size_t)b * 2 + 1) * HWF + i * FW + j];
    float u = (float)j + 0.5f * fx;
    float v = (float)i + 0.5f * fy;
    bool valid = (u >= 0.f) && (u <= (float)(FW - 1)) && (v >= 0.f) && (v <= (float)(FH - 1));
    float x = fminf(fmaxf(u, 0.f), (float)(FW - 1));
    float y = fminf(fmaxf(v, 0.f), (float)(FH - 1));
    int x0 = min((int)x, FW - 2);
    int y0 = min((int)y, FH - 2);
    float wxf = x - (float)x0, wyf = y - (float)y0;
    float w00 = (1.f - wxf) * (1.f - wyf), w01 = wxf * (1.f - wyf);
    float w10 = (1.f - wxf) * wyf, w11 = wxf * wyf;
    if (!valid) { w00 = w01 = w10 = w11 = 0.f; }

    const float* fb = feat + ((size_t)b * CF + g * 12) * HWF + (size_t)y0 * FW + x0;
    float vals[12];
    #pragma unroll
    for (int k = 0; k < 12; k++) {
        const float* p = fb + (size_t)k * HWF;
        f2v r0 = *(const f2v*)p;
        f2v r1 = *(const f2v*)(p + FW);
        vals[k] = w00 * r0.x + w01 * r0.y + w10 * r1.x + w11 * r1.y;
    }

    float* ob = wfeat + ((size_t)b * CF + g * 12) * HWF + (size_t)i * FW + j;
    #pragma unroll
    for (int k = 0; k < 12; k++) ob[(size_t)k * HWF] = vals[k];

    short* xr = xin + (size_t)pix * 128 + g * 12;   // 24B per thread, 8B-aligned
    #pragma unroll
    for (int q2 = 0; q2 < 3; q2++) {
        s4v pk = { (short)f2bf(vals[q2 * 4 + 0]), (short)f2bf(vals[q2 * 4 + 1]),
                   (short)f2bf(vals[q2 * 4 + 2]), (short)f2bf(vals[q2 * 4 + 3]) };
        *(s4v*)(xr + q2 * 4) = pk;
    }
}

// ---------------------------------------------------------------------------
// Weight repack: w[co][ci][3][3] fp32 -> wA[off][co][KSTR] bf16
// ---------------------------------------------------------------------------
__global__ __launch_bounds__(256)
void cvt_w1_kernel(const float* __restrict__ w1, short* __restrict__ wA1) {
    int i = blockIdx.x * 256 + threadIdx.x;
    if (i >= 9 * 96 * 128) return;
    int ci = i & 127;
    int co = (i >> 7) % 96;
    int off = i / (96 * 128);
    float v = (ci < C1) ? w1[((size_t)co * C1 + ci) * 9 + off] : 0.f;
    wA1[i] = (short)f2bf(v);
}
__global__ __launch_bounds__(256)
void cvt_w2_kernel(const float* __restrict__ w2, short* __restrict__ wA2) {
    int i = blockIdx.x * 256 + threadIdx.x;
    if (i >= 9 * 96 * 96) return;
    int ci = i % 96;
    int co = (i / 96) % 96;
    int off = i / (96 * 96);
    wA2[i] = (short)f2bf(w2[((size_t)co * CF + ci) * 9 + off]);
}

// ---------------------------------------------------------------------------
// MFMA implicit-GEMM 3x3 conv (validated R3)
// ---------------------------------------------------------------------------
template <int PASS>
__global__ __launch_bounds__(256)
void conv_mfma_kernel(const short* __restrict__ X,    // [b][h][w][KSTR] bf16
                      const short* __restrict__ W,    // [9][96][KSTR] bf16
                      const float* __restrict__ bias,
                      short* __restrict__ t1out,
                      float* __restrict__ out0) {
    constexpr int KSTR = (PASS == 1) ? 128 : 96;
    constexpr int KC = KSTR / 32;
    __shared__ short Als[96 * LDK];
    __shared__ short Bls[128 * LDK];

    const int bx = blockIdx.x;
    const int w0 = (bx & 1) * 128;
    const int h  = (bx >> 1) & (FH - 1);
    const int b  = bx >> 9;

    const int tid = threadIdx.x;
    const int lane = tid & 63;
    const int wv = tid >> 6;
    const int ln = lane & 15;
    const int q  = lane >> 4;

    f4v acc[6][2];
    #pragma unroll
    for (int mt = 0; mt < 6; mt++)
        #pragma unroll
        for (int nt = 0; nt < 2; nt++)
            acc[mt][nt] = (f4v){0.f, 0.f, 0.f, 0.f};

    const short* Xb = X + (size_t)(b * FH) * FW * KSTR;

    const int an = tid >> 1, ah = tid & 1;

    for (int off = 0; off < 9; ++off) {
        const int dy = off / 3 - 1, dx = off % 3 - 1;
        const int hy = h + dy;
        const bool hok = (hy >= 0) && (hy < FH);
        const short* Xrow = Xb + (size_t)hy * FW * KSTR;
        const short* Woff = W + (size_t)off * 96 * KSTR;
        const int wc = w0 + an + dx;
        const bool cok = hok && (wc >= 0) && (wc < FW);

        for (int kc = 0; kc < KC; ++kc) {
            const int ci0 = kc * 32;
            __syncthreads();
            if (tid < 192) {
                const short* srcA = Woff + (size_t)an * KSTR + ci0 + ah * 16;
                short* dstA = Als + an * LDK + ah * 16;
                *(float4*)dstA = *(const float4*)srcA;
                *(float4*)(dstA + 8) = *(const float4*)(srcA + 8);
            }
            {
                float4 vb0 = {0.f, 0.f, 0.f, 0.f};
                float4 vb1 = {0.f, 0.f, 0.f, 0.f};
                if (cok) {
                    const short* srcB = Xrow + (size_t)wc * KSTR + ci0 + ah * 16;
                    vb0 = *(const float4*)srcB;
                    vb1 = *(const float4*)(srcB + 8);
                }
                short* dstB = Bls + an * LDK + ah * 16;
                *(float4*)dstB = vb0;
                *(float4*)(dstB + 8) = vb1;
            }
            __syncthreads();
            s8v bfr0 = *(const s8v*)(Bls + (wv * 32 + ln) * LDK + q * 8);
            s8v bfr1 = *(const s8v*)(Bls + (wv * 32 + 16 + ln) * LDK + q * 8);
            #pragma unroll
            for (int mt = 0; mt < 6; ++mt) {
                s8v afr = *(const s8v*)(Als + (mt * 16 + ln) * LDK + q * 8);
                acc[mt][0] = __builtin_amdgcn_mfma_f32_16x16x32_bf16(afr, bfr0, acc[mt][0], 0, 0, 0);
                acc[mt][1] = __builtin_amdgcn_mfma_f32_16x16x32_bf16(afr, bfr1, acc[mt][1], 0, 0, 0);
            }
        }
    }

    if (PASS == 1) {
        const size_t rowbase = (size_t)(b * FH + h) * FW;
        #pragma unroll
        for (int nt = 0; nt < 2; ++nt) {
            int pos = w0 + wv * 32 + nt * 16 + ln;
            short* dst = t1out + (rowbase + pos) * CF;
            #pragma unroll
            for (int mt = 0; mt < 6; ++mt) {
                int co0 = mt * 16 + q * 4;
                s4v pk;
                #pragma unroll
                for (int r = 0; r < 4; ++r) {
                    float v = acc[mt][nt][r] + bias[co0 + r];
                    pk[r] = (short)f2bf(fmaxf(v, 0.f));
                }
                *(s4v*)(dst + co0) = pk;
            }
        }
    } else {
        #pragma unroll
        for (int nt = 0; nt < 2; ++nt) {
            int pos = w0 + wv * 32 + nt * 16 + ln;
            #pragma unroll
            for (int mt = 0; mt < 6; ++mt) {
                int co0 = mt * 16 + q * 4;
                #pragma unroll
                for (int r = 0; r < 4; ++r) {
                    size_t o = (size_t)(b * CF + co0 + r) * HWF + (size_t)h * FW + pos;
                    out0[o] += acc[mt][nt][r] + bias[co0 + r];
                }
            }
        }
    }
}

extern "C" void kernel_launch(void* const* d_in, const int* in_sizes, int n_in,
                              void* d_out, int out_size, void* d_ws, size_t ws_size,
                              hipStream_t stream) {
    const float* img  = (const float*)d_in[0];
    const float* feat = (const float*)d_in[1];
    const float* flow = (const float*)d_in[2];
    const float* kp   = (const float*)d_in[3];
    const float* w1   = (const float*)d_in[4];
    const float* b1   = (const float*)d_in[5];
    const float* w2   = (const float*)d_in[6];
    const float* b2   = (const float*)d_in[7];

    float* out0 = (float*)d_out;                       // [B,96,256,256] fp32
    float* out1 = out0 + (size_t)NB * CF * HWF;        // [B,3,512,512]  fp32

    char* wsb = (char*)d_ws;
    short* wA1 = (short*)wsb;                                   //   221,184 B
    short* wA2 = (short*)(wsb + 221184);                        //   165,888 B
    short* xin = (short*)(wsb + 221184 + 165888);               // 67,108,864 B [b][h][w][128]
    char* region = wsb + 221184 + 165888 + 67108864;            // 50,331,648 B shared:
    short* t1cl    = (short*)region;                            //   t1 cl bf16 (convs)
    float* img_row = (float*)region;                            //   12.58 MB (dead before conv1)
    float* flow_s  = (float*)(region + 16777216);               //   2.1 MB (dead before conv1)

    int n_img = NB * HWI;
    hipLaunchKernelGGL(cvt_w1_kernel, dim3((9 * 96 * 128 + 255) / 256), dim3(256), 0, stream, w1, wA1);
    hipLaunchKernelGGL(cvt_w2_kernel, dim3((9 * 96 * 96 + 255) / 256), dim3(256), 0, stream, w2, wA2);
    hipLaunchKernelGGL(lkw_row_kernel, dim3((n_img + 255) / 256), dim3(256), 0, stream,
                       img, flow, kp, img_row);
    hipLaunchKernelGGL(lkw_col_kernel, dim3((n_img + 255) / 256), dim3(256), 0, stream,
                       img_row, kp, out1);
    hipLaunchKernelGGL(downsample2x_kernel, dim3((NB * 2 * HWF + 255) / 256), dim3(256), 0, stream,
                       flow, flow_s, NB * 2, 0.5f);
    hipLaunchKernelGGL(imgdown_cl_kernel, dim3((NB * HWF + 255) / 256), dim3(256), 0, stream,
                       out1, xin);
    hipLaunchKernelGGL(warp_feat_cl_kernel, dim3(NB * HWF * 8 / 256), dim3(256), 0, stream,
                       feat, flow_s, out0, xin);
    hipLaunchKernelGGL((conv_mfma_kernel<1>), dim3(NB * FH * 2), dim3(256), 0, stream,
                       xin, wA1, b1, t1cl, (float*)nullptr);
    hipLaunchKernelGGL((conv_mfma_kernel<2>), dim3(NB * FH * 2), dim3(256), 0, stream,
                       t1cl, wA2, b2, (short*)nullptr, out0);
}